// Round 2
// baseline (303.298 us; speedup 1.0000x reference)
//
#include <hip/hip_runtime.h>

// Fused RK4 step for 2D Burgers-like PDE, periodic BCs, radius-2 stencils.
// Tile 64x64 output, 80x80 staged (halo 8 = 4 stages x radius 2).
// Stage inputs in LDS (in-place update via regs + barriers); u0/v0/acc in regs.
// R2: 512-thread blocks (16 waves/CU), stage-shrinking guards, f4 staging,
//     nontemporal output stores.

typedef float f4 __attribute__((ext_vector_type(4)));

#define LCOLS 88            // 4 pad + 80 + 4 pad
#define LROWS 84            // 2 pad + 80 + 2 pad
#define NBUF  (LROWS*LCOLS) // 7392 floats = 29568 B per field buffer
#define NT    512
#define NQ    4             // ceil(1600 quads / 512 threads)

__global__ __launch_bounds__(NT, 4)
void rk4_stencil(const float* __restrict__ h,
                 const float* __restrict__ sRe, const float* __restrict__ sUA,
                 const float* __restrict__ sUB, const float* __restrict__ sVA,
                 const float* __restrict__ sVB, float* __restrict__ out)
{
    __shared__ __align__(16) float tu[NBUF];
    __shared__ __align__(16) float tv[NBUF];

    const int tid = threadIdx.x;
    const int tc = blockIdx.x, tr = blockIdx.y, bb = blockIdx.z;

    const float Re = sRe[0], UA = sUA[0], UB = sUB[0], VA = sVA[0], VB = sVB[0];
    const float nu = 0.001f / Re;

    // stencil coeffs (already divided by DX / DX^2, DX=0.01)
    const float d1 = 800.f/12.f;          // (8/12)/DX
    const float d2 = 100.f/12.f;          // (1/12)/DX
    const float a1 = (4.f/3.f)*1.0e4f;    // (4/3)/DX^2
    const float a2 = -(1.f/12.f)*1.0e4f;  // (-1/12)/DX^2
    const float a0 = -5.0e4f;             // -5/DX^2 (both axes combined center)

    const f4 z4 = {0.f, 0.f, 0.f, 0.f};

    // zero LDS (pads must be finite; interior overwritten by staging)
    for (int i = tid; i < NBUF/4; i += NT) { ((f4*)tu)[i] = z4; ((f4*)tv)[i] = z4; }
    __syncthreads();

    const size_t plane = 1048576;
    const float* uin = h + (size_t)(bb*2) * plane;
    const float* vin = uin + plane;
    const int base_r = tr*64 - 8, base_c = tc*64 - 8;   // base_c % 4 == 0

    // stage 80x80 u0,v0 into LDS as f4 groups (wrap indexing; groups never
    // straddle the 1024 wrap since base_c,1024 are multiples of 4)
#pragma unroll
    for (int m = 0; m < 4; ++m) {
        int g = tid + NT*m;
        if (g < 1600) {
            int r = g / 20, k = g - r*20;
            int gr = (base_r + r) & 1023;
            int gc = (base_c + 4*k) & 1023;
            int l = (r+2)*LCOLS + 4 + 4*k;
            *(f4*)(tu + l) = *(const f4*)(uin + (size_t)gr*1024 + gc);
            *(f4*)(tv + l) = *(const f4*)(vin + (size_t)gr*1024 + gc);
        }
    }
    __syncthreads();

    // ownership: quad q = tid + NT*j ; quad (qr,qc): row qr in [0,80), cols 4qc..4qc+3
    int  lidx[NQ]; bool has[NQ]; int qrA[NQ], qcA[NQ];
    f4 u0[NQ], v0[NQ], au[NQ], av[NQ];
#pragma unroll
    for (int j = 0; j < NQ; ++j) {
        int q = tid + NT*j;
        has[j] = (q < 1600);
        int qr = q / 20, qc = q - qr*20;
        qrA[j] = qr; qcA[j] = qc;
        lidx[j] = (qr+2)*LCOLS + 4 + 4*qc;
        au[j] = z4; av[j] = z4;
        if (has[j]) {
            u0[j] = *(const f4*)(tu + lidx[j]);
            v0[j] = *(const f4*)(tv + lidx[j]);
        }
    }

    // stage s computes k_{s+1} over region [2(s+1), 80-2(s+1)) rows, quad-rounded cols
    const int rowlo[4] = {2, 4, 6, 8};
    const int rowhi[4] = {78, 76, 74, 72};
    const int qclo[4]  = {0, 1, 1, 2};
    const int qchi[4]  = {20, 19, 19, 18};
    const float csc_t[4] = {0.25f, 0.25f, 0.5f, 0.f}; // DT/2, DT/2, DT, -
    const float wgt_t[4] = {1.f, 2.f, 2.f, 1.f};

#pragma unroll
    for (int s = 0; s < 4; ++s) {
        const float wgt = wgt_t[s];
        const float csc = csc_t[s];
        f4 stu[NQ], stv[NQ];
        bool act[NQ];
#pragma unroll
        for (int j = 0; j < NQ; ++j) {
            act[j] = has[j] && qrA[j] >= rowlo[s] && qrA[j] < rowhi[s]
                            && qcA[j] >= qclo[s]  && qcA[j] < qchi[s];
            if (!act[j]) continue;
            const int l = lidx[j];
            f4 ucc = *(const f4*)(tu+l);
            f4 ucl = *(const f4*)(tu+l-4);
            f4 ucr = *(const f4*)(tu+l+4);
            f4 un1 = *(const f4*)(tu+l-LCOLS);
            f4 us1 = *(const f4*)(tu+l+LCOLS);
            f4 un2 = *(const f4*)(tu+l-2*LCOLS);
            f4 us2 = *(const f4*)(tu+l+2*LCOLS);
            f4 vcc = *(const f4*)(tv+l);
            f4 vcl = *(const f4*)(tv+l-4);
            f4 vcr = *(const f4*)(tv+l+4);
            f4 vn1 = *(const f4*)(tv+l-LCOLS);
            f4 vs1 = *(const f4*)(tv+l+LCOLS);
            f4 vn2 = *(const f4*)(tv+l-2*LCOLS);
            f4 vs2 = *(const f4*)(tv+l+2*LCOLS);
            float hu[8] = {ucl[2],ucl[3],ucc[0],ucc[1],ucc[2],ucc[3],ucr[0],ucr[1]};
            float hv[8] = {vcl[2],vcl[3],vcc[0],vcc[1],vcc[2],vcc[3],vcr[0],vcr[1]};
#pragma unroll
            for (int k = 0; k < 4; ++k) {
                float u = hu[k+2], v = hv[k+2];
                // derivative along rows (axis 2) = reference's K_DX
                float urow = d1*(us1[k]-un1[k]) + d2*(un2[k]-us2[k]);
                float vrow = d1*(vs1[k]-vn1[k]) + d2*(vn2[k]-vs2[k]);
                // derivative along cols (axis 3) = reference's K_DY
                float ucol = d1*(hu[k+3]-hu[k+1]) + d2*(hu[k]-hu[k+4]);
                float vcol = d1*(hv[k+3]-hv[k+1]) + d2*(hv[k]-hv[k+4]);
                float ulap = a1*((un1[k]+us1[k])+(hu[k+1]+hu[k+3]))
                           + a2*((un2[k]+us2[k])+(hu[k]+hu[k+4])) + a0*u;
                float vlap = a1*((vn1[k]+vs1[k])+(hv[k+1]+hv[k+3]))
                           + a2*((vn2[k]+vs2[k])+(hv[k]+hv[k+4])) + a0*v;
                float fu = nu*ulap + UA*(u*urow) + UB*(v*ucol);
                float fv = nu*vlap + VA*(u*vrow) + VB*(v*vcol);
                au[j][k] += wgt*fu;
                av[j][k] += wgt*fv;
                if (s < 3) {
                    stu[j][k] = u0[j][k] + csc*fu;
                    stv[j][k] = v0[j][k] + csc*fv;
                }
            }
        }
        if (s < 3) {
            __syncthreads();   // all reads of t_s done
#pragma unroll
            for (int j = 0; j < NQ; ++j) {
                if (!act[j]) continue;
                *(f4*)(tu+lidx[j]) = stu[j];
                *(f4*)(tv+lidx[j]) = stv[j];
            }
            __syncthreads();   // t_{s+1} visible
        }
    }

    // epilogue: out = u0 + (DT/6)*(k1+2k2+2k3+k4); interior cells [8,72)^2
    float* outu = out + (size_t)(bb*2) * plane;
    float* outv = outu + plane;
#pragma unroll
    for (int j = 0; j < NQ; ++j) {
        if (!has[j]) continue;
        int qr = qrA[j], qc = qcA[j];
        if (qr >= 8 && qr < 72 && qc >= 2 && qc < 18) {
            int gr = tr*64 + qr - 8;
            int gc = tc*64 + 4*qc - 8;
            f4 ru, rv;
#pragma unroll
            for (int k = 0; k < 4; ++k) {
                ru[k] = u0[j][k] + (1.f/12.f)*au[j][k];
                rv[k] = v0[j][k] + (1.f/12.f)*av[j][k];
            }
            __builtin_nontemporal_store(ru, (f4*)(outu + (size_t)gr*1024 + gc));
            __builtin_nontemporal_store(rv, (f4*)(outv + (size_t)gr*1024 + gc));
        }
    }
}

extern "C" void kernel_launch(void* const* d_in, const int* in_sizes, int n_in,
                              void* d_out, int out_size, void* d_ws, size_t ws_size,
                              hipStream_t stream) {
    const float* h   = (const float*)d_in[0];
    const float* sRe = (const float*)d_in[1];
    const float* sUA = (const float*)d_in[2];
    const float* sUB = (const float*)d_in[3];
    const float* sVA = (const float*)d_in[4];
    const float* sVB = (const float*)d_in[5];
    float* o = (float*)d_out;
    rk4_stencil<<<dim3(16,16,8), dim3(NT,1,1), 0, stream>>>(h, sRe, sUA, sUB, sVA, sVB, o);
}

// Round 3
// 210.158 us; speedup vs baseline: 1.4432x; 1.4432x over previous
//
#include <hip/hip_runtime.h>

// Fused RK4 step for 2D Burgers-like PDE, periodic BCs, radius-2 stencils.
// Tile 64x64 output, 80x80 staged (halo 8 = 4 stages x radius 2), in-place LDS
// stage updates. R3: kill register spills -- per-thread persistent state is only
// kprev+acc (u0 reconstructed as t_s - c*kprev); 1024 threads, NQ=2; f2 edge
// reads; direct global store from stage 3.

typedef float f4 __attribute__((ext_vector_type(4)));
typedef float f2 __attribute__((ext_vector_type(2)));

#define LCOLS 88            // 4 pad + 80 + 4 pad
#define LROWS 84            // 2 pad + 80 + 2 pad (pad rows never read; kept for layout)
#define NBUF  (LROWS*LCOLS) // 7392 floats = 29568 B per field
#define NT    1024
#define NQ    2             // 1600 quads / 1024 threads

__global__ __launch_bounds__(NT, 4)
void rk4_stencil(const float* __restrict__ h,
                 const float* __restrict__ sRe, const float* __restrict__ sUA,
                 const float* __restrict__ sUB, const float* __restrict__ sVA,
                 const float* __restrict__ sVB, float* __restrict__ out)
{
    __shared__ __align__(16) float tu[NBUF];
    __shared__ __align__(16) float tv[NBUF];

    const int tid = threadIdx.x;
    const int tc = blockIdx.x, tr = blockIdx.y, bb = blockIdx.z;

    const float Re = sRe[0], UA = sUA[0], UB = sUB[0], VA = sVA[0], VB = sVB[0];
    const float nu = 0.001f / Re;

    const float d1 = 800.f/12.f;          // (8/12)/DX
    const float d2 = 100.f/12.f;          // (1/12)/DX
    const float a1 = (4.f/3.f)*1.0e4f;    // (4/3)/DX^2
    const float a2 = -(1.f/12.f)*1.0e4f;  // (-1/12)/DX^2
    const float a0 = -5.0e4f;             // -5/DX^2 (both axes center)

    const f4 z4 = {0.f, 0.f, 0.f, 0.f};

    // zero ONLY the col pads actually read (LDS cols 0..3 / 84..87, rows 2..81):
    // 80 rows x 2 sides x 2 fields = 320 f4 stores; disjoint from staged interior.
    {
        int i = tid;
        if (i < 320) {
            int row = 2 + (i % 80);
            int rest = i / 80;              // 0..3
            float* p = ((rest >> 1) ? tv : tu) + row*LCOLS + ((rest & 1) ? 84 : 0);
            *(f4*)p = z4;
        }
    }

    const size_t plane = 1048576;
    const float* uin = h + (size_t)(bb*2) * plane;
    const float* vin = uin + plane;
    const int base_r = tr*64 - 8, base_c = tc*64 - 8;   // both multiples of 4 mod wrap

    // stage 80x80 u0,v0 into LDS as f4 groups (wrap indexing; no straddle since
    // base_c and 1024 are multiples of 4)
#pragma unroll
    for (int m = 0; m < 2; ++m) {
        int g = tid + NT*m;
        if (g < 1600) {
            int r = g / 20, k = g - r*20;
            int gr = (base_r + r) & 1023;
            int gc = (base_c + 4*k) & 1023;
            int l = (r+2)*LCOLS + 4 + 4*k;
            *(f4*)(tu + l) = *(const f4*)(uin + (size_t)gr*1024 + gc);
            *(f4*)(tv + l) = *(const f4*)(vin + (size_t)gr*1024 + gc);
        }
    }
    __syncthreads();

    // ownership: quad q = tid + NT*j ; quad (qr,qc): row qr in [0,80), cols 4qc..4qc+3
    int  lidx[NQ]; bool has[NQ]; int qrA[NQ], qcA[NQ];
    f4 ku[NQ], kv[NQ], au[NQ], av[NQ];   // prev-stage k and RK accumulator
#pragma unroll
    for (int j = 0; j < NQ; ++j) {
        int q = tid + NT*j;
        has[j] = (q < 1600);
        int qr = q / 20, qc = q - qr*20;
        qrA[j] = qr; qcA[j] = qc;
        lidx[j] = (qr+2)*LCOLS + 4 + 4*qc;
        ku[j] = z4; kv[j] = z4; au[j] = z4; av[j] = z4;
    }

    // stage s computes k_{s+1}; valid region shrinks 2 cells/stage (quad-rounded cols)
    const int rowlo[4] = {2, 4, 6, 8};
    const int rowhi[4] = {78, 76, 74, 72};
    const int qclo[4]  = {0, 1, 1, 2};
    const int qchi[4]  = {20, 19, 19, 18};
    const float csub_t[4] = {0.f, 0.25f, 0.25f, 0.5f};  // c_{s-1}: undo prev update
    const float cadd_t[4] = {0.25f, 0.25f, 0.5f, 0.f};  // c_s: apply this update
    const float wgt_t[4]  = {1.f, 2.f, 2.f, 1.f};

    float* outu = out + (size_t)(bb*2) * plane;
    float* outv = outu + plane;

#pragma unroll
    for (int s = 0; s < 4; ++s) {
        const float wgt  = wgt_t[s];
        const float csub = csub_t[s];
        const float cadd = cadd_t[s];
        f4 stu[NQ], stv[NQ];
        bool act[NQ];
#pragma unroll
        for (int j = 0; j < NQ; ++j) {
            act[j] = has[j] && qrA[j] >= rowlo[s] && qrA[j] < rowhi[s]
                            && qcA[j] >= qclo[s]  && qcA[j] < qchi[s];
            if (!act[j]) continue;
            const int l = lidx[j];
            f4 ucc = *(const f4*)(tu+l);
            f2 ul2 = *(const f2*)(tu+l-2);
            f2 ur2 = *(const f2*)(tu+l+4);
            f4 un1 = *(const f4*)(tu+l-LCOLS);
            f4 us1 = *(const f4*)(tu+l+LCOLS);
            f4 un2 = *(const f4*)(tu+l-2*LCOLS);
            f4 us2 = *(const f4*)(tu+l+2*LCOLS);
            f4 vcc = *(const f4*)(tv+l);
            f2 vl2 = *(const f2*)(tv+l-2);
            f2 vr2 = *(const f2*)(tv+l+4);
            f4 vn1 = *(const f4*)(tv+l-LCOLS);
            f4 vs1 = *(const f4*)(tv+l+LCOLS);
            f4 vn2 = *(const f4*)(tv+l-2*LCOLS);
            f4 vs2 = *(const f4*)(tv+l+2*LCOLS);
            float hu[8] = {ul2[0],ul2[1],ucc[0],ucc[1],ucc[2],ucc[3],ur2[0],ur2[1]};
            float hv[8] = {vl2[0],vl2[1],vcc[0],vcc[1],vcc[2],vcc[3],vr2[0],vr2[1]};
            f4 ou, ov;   // stage-3 output staging
#pragma unroll
            for (int k = 0; k < 4; ++k) {
                float u = hu[k+2], v = hv[k+2];
                // row-direction derivative (axis 2) = reference K_DX
                float urow = d1*(us1[k]-un1[k]) + d2*(un2[k]-us2[k]);
                float vrow = d1*(vs1[k]-vn1[k]) + d2*(vn2[k]-vs2[k]);
                // col-direction derivative (axis 3) = reference K_DY
                float ucol = d1*(hu[k+3]-hu[k+1]) + d2*(hu[k]-hu[k+4]);
                float vcol = d1*(hv[k+3]-hv[k+1]) + d2*(hv[k]-hv[k+4]);
                float ulap = a1*((un1[k]+us1[k])+(hu[k+1]+hu[k+3]))
                           + a2*((un2[k]+us2[k])+(hu[k]+hu[k+4])) + a0*u;
                float vlap = a1*((vn1[k]+vs1[k])+(hv[k+1]+hv[k+3]))
                           + a2*((vn2[k]+vs2[k])+(hv[k]+hv[k+4])) + a0*v;
                float fu = nu*ulap + UA*(u*urow) + UB*(v*ucol);
                float fv = nu*vlap + VA*(u*vrow) + VB*(v*vcol);
                float kuold = ku[j][k], kvold = kv[j][k];
                if (s == 3) {
                    // u0 = t3 - DT*k3 ; out = u0 + (DT/6)*(k1+2k2+2k3+k4)
                    ou[k] = (u - 0.5f*kuold) + (1.f/12.f)*(au[j][k] + fu);
                    ov[k] = (v - 0.5f*kvold) + (1.f/12.f)*(av[j][k] + fv);
                } else {
                    au[j][k] += wgt*fu;
                    av[j][k] += wgt*fv;
                    // t_{s+1} = u0 + cadd*k_new, with u0 = t_s - csub*k_prev
                    stu[j][k] = (u - csub*kuold) + cadd*fu;
                    stv[j][k] = (v - csub*kvold) + cadd*fv;
                    ku[j][k] = fu;
                    kv[j][k] = fv;
                }
            }
            if (s == 3) {
                int gr = tr*64 + qrA[j] - 8;
                int gc = tc*64 + 4*qcA[j] - 8;
                __builtin_nontemporal_store(ou, (f4*)(outu + (size_t)gr*1024 + gc));
                __builtin_nontemporal_store(ov, (f4*)(outv + (size_t)gr*1024 + gc));
            }
        }
        if (s < 3) {
            __syncthreads();   // all reads of t_s done
#pragma unroll
            for (int j = 0; j < NQ; ++j) {
                if (!act[j]) continue;
                *(f4*)(tu+lidx[j]) = stu[j];
                *(f4*)(tv+lidx[j]) = stv[j];
            }
            __syncthreads();   // t_{s+1} visible
        }
    }
}

extern "C" void kernel_launch(void* const* d_in, const int* in_sizes, int n_in,
                              void* d_out, int out_size, void* d_ws, size_t ws_size,
                              hipStream_t stream) {
    const float* h   = (const float*)d_in[0];
    const float* sRe = (const float*)d_in[1];
    const float* sUA = (const float*)d_in[2];
    const float* sUB = (const float*)d_in[3];
    const float* sVA = (const float*)d_in[4];
    const float* sVB = (const float*)d_in[5];
    float* o = (float*)d_out;
    rk4_stencil<<<dim3(16,16,8), dim3(NT,1,1), 0, stream>>>(h, sRe, sUA, sUB, sVA, sVB, o);
}